// Round 3
// baseline (308.141 us; speedup 1.0000x reference)
//
#include <hip/hip_runtime.h>
#include <hip/hip_bf16.h>

// ---------- types / helpers ----------
typedef __attribute__((ext_vector_type(8))) short short8;     // 8 bf16 = 4 VGPRs (MFMA A/B frag)
typedef __attribute__((ext_vector_type(4))) float f32x4;      // MFMA C/D frag

__device__ __forceinline__ float bf2f(unsigned short s) {
    union { unsigned int u; float f; } v; v.u = ((unsigned int)s) << 16; return v.f;
}
__device__ __forceinline__ unsigned short f2bf(float f) {  // round-to-nearest-even
    union { float f; unsigned int u; } v; v.f = f;
    unsigned int u = v.u;
    unsigned int r = (u + 0x7FFFu + ((u >> 16) & 1u)) >> 16;
    return (unsigned short)r;
}
__device__ __forceinline__ void gload_lds16(const void* g, void* l) {
    // async global->LDS, 16B/lane; LDS dest = wave-uniform base + lane*16
    __builtin_amdgcn_global_load_lds((const __attribute__((address_space(1))) void*)g,
                                     (__attribute__((address_space(3))) void*)l, 16, 0, 0);
}

// ---------- constants ----------
#define BATCH 256
#define CHAN  768
#define HW    196
#define SPS   196
#define HID   512
#define MROWS 50176   // BATCH*SPS
#define K1    1536    // 2*CHAN

// ---------- weight prep ----------
// in [K][N] fp32 -> out [N][K] bf16  (N-major so B-frag reads are contiguous)
__global__ void transpose_cast(const float* __restrict__ in, unsigned short* __restrict__ out,
                               int K, int N) {
    int idx = blockIdx.x * 256 + threadIdx.x;
    if (idx >= K * N) return;
    int n = idx / K, k = idx - n * K;
    out[idx] = f2bf(in[(size_t)k * N + n]);
}

// ---------- gather + out-init: feats bf16; out[0:2M)=b3 (pred init); out[2M:4M)=deltaxy ----------
__global__ __launch_bounds__(256) void gather_feats(const float* __restrict__ x,
                                                    const int* __restrict__ pxs,
                                                    const int* __restrict__ pys,
                                                    const float* __restrict__ b3,
                                                    unsigned short* __restrict__ feats,
                                                    float* __restrict__ out) {
    __shared__ float lds[64 * 197];   // pitch 197: stride-5 banks, conflict-free
    int chunk = blockIdx.x;           // 0..11 (64-channel chunk)
    int b     = blockIdx.y;           // 0..255
    int c0 = chunk * 64;
    const float* xb = x + ((size_t)b * CHAN + c0) * HW;
    for (int t = threadIdx.x; t < 64 * HW; t += 256) {
        int j = t / HW, p = t - j * HW;
        lds[j * 197 + p] = xb[t];     // coalesced read of 64 full channels
    }
    if (chunk == 0) {                 // per-batch: init pred rows to b3, write deltaxy
        float b30 = b3[0], b31 = b3[1];
        for (int i = threadIdx.x; i < SPS * 2; i += 256) {
            int idx = b * SPS * 2 + i;
            out[idx] = (i & 1) ? b31 : b30;                          // pred init (atomics add on top)
            out[MROWS * 2 + idx] = (float)(pxs[idx] - pys[idx]) + 13.0f;  // (H-1)=13
        }
    }
    __syncthreads();
    int w = threadIdx.x >> 6, lane = threadIdx.x & 63;
    for (int s = w; s < SPS; s += 4) {
        int base = (b * SPS + s) * 2;
        int ix = pxs[base] * 14 + pxs[base + 1];
        int iy = pys[base] * 14 + pys[base + 1];
        size_t ro = (size_t)(b * SPS + s) * K1;
        feats[ro + c0 + lane]        = f2bf(lds[lane * 197 + ix]);  // 128B coalesced store
        feats[ro + CHAN + c0 + lane] = f2bf(lds[lane * 197 + iy]);
    }
}

// ---------- 128x128 bf16 MFMA GEMM, 2-phase double-buffered, XOR-swizzled LDS, XCD swizzle ----
// C = relu(A @ Bt^T + bias); A[M][K], Bt[N][K] row-major bf16.
// 1-D grid; bijective XCD remap (nwg%8==0): each XCD owns a contiguous mTile range,
// the nTilesN blocks sharing an A-tile are co-XCD and temporally adjacent -> A L2-hits.
// LDS tile [128][64 bf16]: slot(row, c) holds global 16B-chunk (c ^ (row&7))  [T2 both-sides swizzle]
// predMode: instead of storing C, accumulate pred = relu(C)@W3 into out via atomics (bias=b2).
__global__ __launch_bounds__(256) void gemm_bias_relu(const unsigned short* __restrict__ A,
                                                      const unsigned short* __restrict__ Bt,
                                                      const float* __restrict__ bias,
                                                      unsigned short* __restrict__ C,
                                                      const float* __restrict__ W3,
                                                      float* __restrict__ out,
                                                      int Kd, int N, int nTilesN, int predMode) {
    __shared__ unsigned short Asm[2][128 * 64];
    __shared__ unsigned short Bsm[2][128 * 64];
    int t = threadIdx.x;
    int w = t >> 6, lane = t & 63;
    int wr = w >> 1, wc = w & 1;             // 2x2 wave grid, each wave 64x64
    int lr = lane & 15, lk = lane >> 4;
    int bid = blockIdx.x;
    int swz = (bid & 7) * (gridDim.x >> 3) + (bid >> 3);   // XCD-chunked remap (T1)
    int nTile = swz & (nTilesN - 1);
    int mTile = swz / nTilesN;
    int mBase = mTile * 128;
    int nBase = nTile * 128;
    f32x4 acc[4][4] = {};
    int nK = Kd >> 6;

    // stage one K-tile (A+B) into buffer `buf` with inverse-swizzled global source.
    auto stage = [&](int buf, int kt) {
        int k0 = kt << 6;
        #pragma unroll
        for (int i = 0; i < 4; ++i) {
            int linear = i * 256 + t;
            int row  = linear >> 3;
            int cs   = (linear & 7) ^ (row & 7);    // inverse-swizzled source chunk
            gload_lds16((const char*)(A  + ((size_t)(mBase + row) * Kd + k0 + cs * 8)),
                        (char*)Asm[buf] + i * 4096 + w * 1024);
            gload_lds16((const char*)(Bt + ((size_t)(nBase + row) * Kd + k0 + cs * 8)),
                        (char*)Bsm[buf] + i * 4096 + w * 1024);
        }
    };
    // compute one K-tile from buffer `buf`; swizzled ds_read addresses.
    auto compute = [&](int buf) {
        #pragma unroll
        for (int kk = 0; kk < 2; ++kk) {
            short8 af[4], bfr[4];
            #pragma unroll
            for (int m = 0; m < 4; ++m) {
                int row = wr * 64 + m * 16 + lr;
                int q = (kk * 4 + lk) ^ (row & 7);              // swizzled chunk
                af[m] = *(const short8*)(&Asm[buf][row * 64 + q * 8]);
            }
            #pragma unroll
            for (int n = 0; n < 4; ++n) {
                int row = wc * 64 + n * 16 + lr;
                int q = (kk * 4 + lk) ^ (row & 7);
                bfr[n] = *(const short8*)(&Bsm[buf][row * 64 + q * 8]);
            }
            #pragma unroll
            for (int m = 0; m < 4; ++m)
                #pragma unroll
                for (int n = 0; n < 4; ++n)
                    acc[m][n] = __builtin_amdgcn_mfma_f32_16x16x32_bf16(af[m], bfr[n], acc[m][n], 0, 0, 0);
        }
    };

    stage(0, 0);
    __syncthreads();                 // drains vmcnt(0): tile 0 resident
    int cur = 0;
    for (int kt = 0; kt + 1 < nK; ++kt) {
        stage(cur ^ 1, kt + 1);      // issue next tile's loads; in flight during compute
        compute(cur);
        __syncthreads();             // drains vmcnt(0) (next tile ready) + all lanes done reading cur
        cur ^= 1;
    }
    compute(cur);

    if (!predMode) {
        // epilogue: bias + relu + bf16 store.  C row=(lane>>4)*4+j, col=lane&15 (m89-verified)
        #pragma unroll
        for (int n = 0; n < 4; ++n) {
            int c = nBase + wc * 64 + n * 16 + lr;
            float bv = bias[c];
            #pragma unroll
            for (int m = 0; m < 4; ++m) {
                int r0 = mBase + wr * 64 + m * 16 + lk * 4;
                #pragma unroll
                for (int j = 0; j < 4; ++j)
                    C[(size_t)(r0 + j) * N + c] = f2bf(fmaxf(acc[m][n][j] + bv, 0.f));
            }
        }
    } else {
        // fused final layer: pred[r][o] += sum_c relu(acc+b2)[r][c] * W3[c][o]
        float w3v[4][2], bv[4];
        #pragma unroll
        for (int n = 0; n < 4; ++n) {
            int c = nBase + wc * 64 + n * 16 + lr;
            w3v[n][0] = W3[c * 2 + 0];
            w3v[n][1] = W3[c * 2 + 1];
            bv[n] = bias[c];
        }
        #pragma unroll
        for (int m = 0; m < 4; ++m) {
            #pragma unroll
            for (int j = 0; j < 4; ++j) {
                float p0 = 0.f, p1 = 0.f;
                #pragma unroll
                for (int n = 0; n < 4; ++n) {
                    float v = fmaxf(acc[m][n][j] + bv[n], 0.f);
                    p0 += v * w3v[n][0];
                    p1 += v * w3v[n][1];
                }
                #pragma unroll
                for (int msk = 1; msk < 16; msk <<= 1) {   // reduce over the 16 lr-lanes (same row)
                    p0 += __shfl_xor(p0, msk);
                    p1 += __shfl_xor(p1, msk);
                }
                if (lr == 0) {
                    int r = mBase + wr * 64 + m * 16 + lk * 4 + j;
                    atomicAdd(&out[r * 2 + 0], p0);
                    atomicAdd(&out[r * 2 + 1], p1);
                }
            }
        }
    }
}

// ---------- launch ----------
extern "C" void kernel_launch(void* const* d_in, const int* in_sizes, int n_in,
                              void* d_out, int out_size, void* d_ws, size_t ws_size,
                              hipStream_t stream) {
    const float* x  = (const float*)d_in[0];
    const float* W1 = (const float*)d_in[1];
    const float* b1 = (const float*)d_in[2];
    const float* W2 = (const float*)d_in[3];
    const float* b2 = (const float*)d_in[4];
    const float* W3 = (const float*)d_in[5];
    const float* b3 = (const float*)d_in[6];
    const int*  pxs = (const int*)d_in[7];
    const int*  pys = (const int*)d_in[8];
    float* out = (float*)d_out;
    char* ws = (char*)d_ws;

    // ws layout (bytes)
    unsigned short* W1t   = (unsigned short*)(ws + 0);          // 512x1536 bf16 = 1,572,864
    unsigned short* W2t   = (unsigned short*)(ws + 1572864);    // 512x512  bf16 =   524,288
    unsigned short* h1    = (unsigned short*)(ws + 2099200);    // 50176x512 bf16 = 51,380,224
    unsigned short* feats = (unsigned short*)(ws + 53479424);   // 50176x1536 bf16 = 154,140,672

    transpose_cast<<<(K1 * HID + 255) / 256, 256, 0, stream>>>(W1, W1t, K1, HID);
    transpose_cast<<<(HID * HID + 255) / 256, 256, 0, stream>>>(W2, W2t, HID, HID);
    // gather also initializes out: pred rows = b3 (GEMM2 atomics accumulate), deltaxy written
    gather_feats<<<dim3(12, BATCH), 256, 0, stream>>>(x, pxs, pys, b3, feats, out);
    // GEMM1: h1 = relu(feats @ W1t^T + b1)       grid = 392 mTiles * 4 nTiles = 1568 (%8==0)
    gemm_bias_relu<<<(MROWS / 128) * (HID / 128), 256, 0, stream>>>(
        feats, W1t, b1, h1, nullptr, nullptr, K1, HID, HID / 128, 0);
    // GEMM2 (+fused GEMM3): out[0:2M) += relu(h1 @ W2t^T + b2) @ W3
    gemm_bias_relu<<<(MROWS / 128) * (HID / 128), 256, 0, stream>>>(
        h1, W2t, b2, nullptr, W3, out, HID, HID, HID / 128, 1);
}

// Round 4
// 282.422 us; speedup vs baseline: 1.0911x; 1.0911x over previous
//
#include <hip/hip_runtime.h>
#include <hip/hip_bf16.h>

// ---------- types / helpers ----------
typedef __attribute__((ext_vector_type(8))) short short8;     // 8 bf16 = 4 VGPRs (MFMA A/B frag)
typedef __attribute__((ext_vector_type(4))) float f32x4;      // MFMA C/D frag

__device__ __forceinline__ float bf2f(unsigned short s) {
    union { unsigned int u; float f; } v; v.u = ((unsigned int)s) << 16; return v.f;
}
__device__ __forceinline__ unsigned short f2bf(float f) {  // round-to-nearest-even
    union { float f; unsigned int u; } v; v.f = f;
    unsigned int u = v.u;
    unsigned int r = (u + 0x7FFFu + ((u >> 16) & 1u)) >> 16;
    return (unsigned short)r;
}
__device__ __forceinline__ void gload_lds16(const void* g, void* l) {
    // async global->LDS, 16B/lane; LDS dest = wave-uniform base + lane*16
    __builtin_amdgcn_global_load_lds((const __attribute__((address_space(1))) void*)g,
                                     (__attribute__((address_space(3))) void*)l, 16, 0, 0);
}

// ---------- constants ----------
#define BATCH 256
#define CHAN  768
#define HW    196
#define SPS   196
#define HID   512
#define MROWS 50176   // BATCH*SPS
#define K1    1536    // 2*CHAN

// GEMM geometry: BM=256, BN=128, BK=64; 8 waves (4M x 2N), per-wave 64x64.
// LDS: 3 rotating buffers x (A 32KB + B 16KB) = 144KB dynamic.
#define BUFB  49152
#define NTN   4       // nTiles in N for both GEMMs (512/128)

// ---------- weight prep ----------
// in [K][N] fp32 -> out [N][K] bf16  (N-major so B-frag reads are contiguous)
__global__ void transpose_cast(const float* __restrict__ in, unsigned short* __restrict__ out,
                               int K, int N) {
    int idx = blockIdx.x * 256 + threadIdx.x;
    if (idx >= K * N) return;
    int n = idx / K, k = idx - n * K;
    out[idx] = f2bf(in[(size_t)k * N + n]);
}

// ---------- gather + out-init: feats bf16; out[0:2M)=b3 (pred init); out[2M:4M)=deltaxy ----------
__global__ __launch_bounds__(256) void gather_feats(const float* __restrict__ x,
                                                    const int* __restrict__ pxs,
                                                    const int* __restrict__ pys,
                                                    const float* __restrict__ b3,
                                                    unsigned short* __restrict__ feats,
                                                    float* __restrict__ out) {
    __shared__ float lds[64 * 197];   // pitch 197: stride-5 banks, conflict-free
    int chunk = blockIdx.x;           // 0..11 (64-channel chunk)
    int b     = blockIdx.y;           // 0..255
    int c0 = chunk * 64;
    const float* xb = x + ((size_t)b * CHAN + c0) * HW;
    for (int t = threadIdx.x; t < 64 * HW; t += 256) {
        int j = t / HW, p = t - j * HW;
        lds[j * 197 + p] = xb[t];     // coalesced read of 64 full channels
    }
    if (chunk == 0) {                 // per-batch: init pred rows to b3, write deltaxy
        float b30 = b3[0], b31 = b3[1];
        for (int i = threadIdx.x; i < SPS * 2; i += 256) {
            int idx = b * SPS * 2 + i;
            out[idx] = (i & 1) ? b31 : b30;                          // pred init (atomics add on top)
            out[MROWS * 2 + idx] = (float)(pxs[idx] - pys[idx]) + 13.0f;  // (H-1)=13
        }
    }
    __syncthreads();
    int w = threadIdx.x >> 6, lane = threadIdx.x & 63;
    for (int s = w; s < SPS; s += 4) {
        int base = (b * SPS + s) * 2;
        int ix = pxs[base] * 14 + pxs[base + 1];
        int iy = pys[base] * 14 + pys[base + 1];
        size_t ro = (size_t)(b * SPS + s) * K1;
        feats[ro + c0 + lane]        = f2bf(lds[lane * 197 + ix]);  // 128B coalesced store
        feats[ro + CHAN + c0 + lane] = f2bf(lds[lane * 197 + iy]);
    }
}

// ---------- 256x128 bf16 MFMA GEMM, 3-buffer rotation + counted vmcnt (T4), T2 swizzle, T5 ----
// C = relu(A @ Bt^T + bias); A[M][K], Bt[N][K] row-major bf16.
// Grid 1-D, nTile fastest (R2's proven layout, no XCD chunking).
// Pipeline: stage(t+2)->buf[(t+2)%3] issued BEFORE compute(t); group end waits vmcnt(6)
// (t+2's 6 loads may fly; t+1 resident) + raw s_barrier. Stage never touches the buffer
// being read (3-way rotation) -> no LDS write/read hazard by construction.
// LDS half: slot(row, c16) holds global chunk c16 ^ (row&7)  [T2 both-sides swizzle]
// predMode: accumulate pred = relu(C)@W3 into out via atomics (bias=b2) instead of storing C.
__global__ __launch_bounds__(512) void gemm_bias_relu(const unsigned short* __restrict__ A,
                                                      const unsigned short* __restrict__ Bt,
                                                      const float* __restrict__ bias,
                                                      unsigned short* __restrict__ C,
                                                      const float* __restrict__ W3,
                                                      float* __restrict__ out,
                                                      int Kd, int N, int predMode) {
    extern __shared__ char smem[];    // 3 * (A[256][64] + B[128][64]) bf16 = 147456 B
    int t = threadIdx.x;
    int wid = t >> 6, lane = t & 63;
    int wr = wid >> 1, wc = wid & 1;             // 4M x 2N wave grid, each wave 64x64
    int lr = lane & 15, lk = lane >> 4;
    int bid = blockIdx.x;
    int nTile = bid & (NTN - 1);                 // nTile fastest: A-sharers adjacent
    int mTile = bid >> 2;
    int mBase = mTile * 256;
    int nBase = nTile * 128;
    f32x4 acc[4][4] = {};
    int nK = Kd >> 6;

    // stage K-tile tt into buf[tt%3]; 6 loads/thread (A:4, B:2); inverse-swizzled source
    auto stage = [&](int tt) {
        char* Ab = smem + (tt % 3) * BUFB;
        char* Bb = Ab + 32768;
        int k0 = tt << 6;
        #pragma unroll
        for (int i = 0; i < 4; ++i) {
            int lin = i * 512 + t;
            int row = lin >> 3;
            int cs  = (lin & 7) ^ (row & 7);
            gload_lds16((const char*)(A + ((size_t)(mBase + row) * Kd + k0 + cs * 8)),
                        Ab + lin * 16);
        }
        #pragma unroll
        for (int i = 0; i < 2; ++i) {
            int lin = i * 512 + t;
            int row = lin >> 3;
            int cs  = (lin & 7) ^ (row & 7);
            gload_lds16((const char*)(Bt + ((size_t)(nBase + row) * Kd + k0 + cs * 8)),
                        Bb + lin * 16);
        }
    };
    // compute K-tile tt from buf[tt%3]; swizzled ds_read addresses
    auto compute = [&](int tt) {
        const unsigned short* Ab = (const unsigned short*)(smem + (tt % 3) * BUFB);
        const unsigned short* Bb = Ab + 16384;
        short8 af[2][4], bfr[2][4];
        #pragma unroll
        for (int kk = 0; kk < 2; ++kk) {
            int q = ((kk * 4 + lk) ^ (lr & 7)) * 8;
            #pragma unroll
            for (int m = 0; m < 4; ++m)
                af[kk][m] = *(const short8*)(Ab + (wr * 64 + m * 16 + lr) * 64 + q);
            #pragma unroll
            for (int n = 0; n < 4; ++n)
                bfr[kk][n] = *(const short8*)(Bb + (wc * 64 + n * 16 + lr) * 64 + q);
        }
        __builtin_amdgcn_s_setprio(1);
        #pragma unroll
        for (int kk = 0; kk < 2; ++kk)
            #pragma unroll
            for (int m = 0; m < 4; ++m)
                #pragma unroll
                for (int n = 0; n < 4; ++n)
                    acc[m][n] = __builtin_amdgcn_mfma_f32_16x16x32_bf16(af[kk][m], bfr[kk][n], acc[m][n], 0, 0, 0);
        __builtin_amdgcn_s_setprio(0);
    };

    // prologue: tiles 0,1 staged (12 loads); wait all but newest 6 -> tile 0 resident
    stage(0);
    stage(1);
    asm volatile("s_waitcnt vmcnt(6)" ::: "memory");
    __builtin_amdgcn_s_barrier();

    for (int tt = 0; tt < nK; ++tt) {
        if (tt + 2 < nK) stage(tt + 2);          // issue-early: flies under compute
        compute(tt);
        if (tt + 2 < nK) { asm volatile("s_waitcnt vmcnt(6)" ::: "memory"); }
        else             { asm volatile("s_waitcnt vmcnt(0)" ::: "memory"); }
        __builtin_amdgcn_s_barrier();
    }

    if (!predMode) {
        // epilogue: bias + relu + bf16 store.  C row=(lane>>4)*4+j, col=lane&15 (m89-verified)
        #pragma unroll
        for (int n = 0; n < 4; ++n) {
            int c = nBase + wc * 64 + n * 16 + lr;
            float bv = bias[c];
            #pragma unroll
            for (int m = 0; m < 4; ++m) {
                int r0 = mBase + wr * 64 + m * 16 + lk * 4;
                #pragma unroll
                for (int j = 0; j < 4; ++j)
                    C[(size_t)(r0 + j) * N + c] = f2bf(fmaxf(acc[m][n][j] + bv, 0.f));
            }
        }
    } else {
        // fused final layer: pred[r][o] += sum_c relu(acc+b2)[r][c] * W3[c][o]
        float w3v[4][2], bv[4];
        #pragma unroll
        for (int n = 0; n < 4; ++n) {
            int c = nBase + wc * 64 + n * 16 + lr;
            w3v[n][0] = W3[c * 2 + 0];
            w3v[n][1] = W3[c * 2 + 1];
            bv[n] = bias[c];
        }
        #pragma unroll
        for (int m = 0; m < 4; ++m) {
            #pragma unroll
            for (int j = 0; j < 4; ++j) {
                float p0 = 0.f, p1 = 0.f;
                #pragma unroll
                for (int n = 0; n < 4; ++n) {
                    float v = fmaxf(acc[m][n][j] + bv[n], 0.f);
                    p0 += v * w3v[n][0];
                    p1 += v * w3v[n][1];
                }
                #pragma unroll
                for (int msk = 1; msk < 16; msk <<= 1) {   // reduce over the 16 lr-lanes (same row)
                    p0 += __shfl_xor(p0, msk);
                    p1 += __shfl_xor(p1, msk);
                }
                if (lr == 0) {
                    int r = mBase + wr * 64 + m * 16 + lk * 4 + j;
                    atomicAdd(&out[r * 2 + 0], p0);
                    atomicAdd(&out[r * 2 + 1], p1);
                }
            }
        }
    }
}

// ---------- launch ----------
extern "C" void kernel_launch(void* const* d_in, const int* in_sizes, int n_in,
                              void* d_out, int out_size, void* d_ws, size_t ws_size,
                              hipStream_t stream) {
    const float* x  = (const float*)d_in[0];
    const float* W1 = (const float*)d_in[1];
    const float* b1 = (const float*)d_in[2];
    const float* W2 = (const float*)d_in[3];
    const float* b2 = (const float*)d_in[4];
    const float* W3 = (const float*)d_in[5];
    const float* b3 = (const float*)d_in[6];
    const int*  pxs = (const int*)d_in[7];
    const int*  pys = (const int*)d_in[8];
    float* out = (float*)d_out;
    char* ws = (char*)d_ws;

    // ws layout (bytes)
    unsigned short* W1t   = (unsigned short*)(ws + 0);          // 512x1536 bf16 = 1,572,864
    unsigned short* W2t   = (unsigned short*)(ws + 1572864);    // 512x512  bf16 =   524,288
    unsigned short* h1    = (unsigned short*)(ws + 2099200);    // 50176x512 bf16 = 51,380,224
    unsigned short* feats = (unsigned short*)(ws + 53479424);   // 50176x1536 bf16 = 154,140,672

    // allow 144KB dynamic LDS (attribute set is not a stream op; safe under capture)
    hipFuncSetAttribute((const void*)gemm_bias_relu,
                        hipFuncAttributeMaxDynamicSharedMemorySize, 3 * BUFB);

    transpose_cast<<<(K1 * HID + 255) / 256, 256, 0, stream>>>(W1, W1t, K1, HID);
    transpose_cast<<<(HID * HID + 255) / 256, 256, 0, stream>>>(W2, W2t, HID, HID);
    // gather also initializes out: pred rows = b3 (GEMM2 atomics accumulate), deltaxy written
    gather_feats<<<dim3(12, BATCH), 256, 0, stream>>>(x, pxs, pys, b3, feats, out);
    // GEMM1: h1 = relu(feats @ W1t^T + b1)   grid = 196 mTiles * 4 nTiles = 784
    gemm_bias_relu<<<(MROWS / 256) * NTN, 512, 3 * BUFB, stream>>>(
        feats, W1t, b1, h1, nullptr, nullptr, K1, HID, 0);
    // GEMM2 (+fused GEMM3): out[0:2M) += relu(h1 @ W2t^T + b2) @ W3
    gemm_bias_relu<<<(MROWS / 256) * NTN, 512, 3 * BUFB, stream>>>(
        h1, W2t, b2, nullptr, W3, out, HID, HID, 1);
}

// Round 5
// 238.965 us; speedup vs baseline: 1.2895x; 1.1819x over previous
//
#include <hip/hip_runtime.h>
#include <hip/hip_bf16.h>

// ---------- types / helpers ----------
typedef __attribute__((ext_vector_type(8))) short short8;     // 8 bf16 = 4 VGPRs (MFMA A/B frag)
typedef __attribute__((ext_vector_type(4))) float f32x4;      // MFMA C/D frag

__device__ __forceinline__ float bf2f(unsigned short s) {
    union { unsigned int u; float f; } v; v.u = ((unsigned int)s) << 16; return v.f;
}
__device__ __forceinline__ unsigned short f2bf(float f) {  // round-to-nearest-even
    union { float f; unsigned int u; } v; v.f = f;
    unsigned int u = v.u;
    unsigned int r = (u + 0x7FFFu + ((u >> 16) & 1u)) >> 16;
    return (unsigned short)r;
}
__device__ __forceinline__ void gload_lds16(const void* g, void* l) {
    // async global->LDS, 16B/lane; LDS dest = wave-uniform base + lane*16
    __builtin_amdgcn_global_load_lds((const __attribute__((address_space(1))) void*)g,
                                     (__attribute__((address_space(3))) void*)l, 16, 0, 0);
}

// ---------- constants ----------
#define BATCH 256
#define CHAN  768
#define HW    196
#define SPS   196
#define HID   512
#define MROWS 50176   // BATCH*SPS
#define K1    1536    // 2*CHAN

// GEMM geometry: BM=128, BN=512 (FULL width -> A staged exactly once), BK=64.
// 8 waves (2M x 4N), per-wave 64x128 output (acc[4][8]).
// LDS: 2 x (A 128x64 16KB + B 512x64 64KB) = 163840 B = the full 160KB pool.
#define ABUF  16384
#define BBUF  65536
#define BUFB  (ABUF + BBUF)

// ---------- weight prep ----------
// in [K][N] fp32 -> out [N][K] bf16  (N-major so B-frag reads are contiguous)
__global__ void transpose_cast(const float* __restrict__ in, unsigned short* __restrict__ out,
                               int K, int N) {
    int idx = blockIdx.x * 256 + threadIdx.x;
    if (idx >= K * N) return;
    int n = idx / K, k = idx - n * K;
    out[idx] = f2bf(in[(size_t)k * N + n]);
}

// ---------- gather + out-init: feats bf16; out[0:2M)=b3 (pred init); out[2M:4M)=deltaxy ----------
__global__ __launch_bounds__(256) void gather_feats(const float* __restrict__ x,
                                                    const int* __restrict__ pxs,
                                                    const int* __restrict__ pys,
                                                    const float* __restrict__ b3,
                                                    unsigned short* __restrict__ feats,
                                                    float* __restrict__ out) {
    __shared__ float lds[64 * 197];   // pitch 197: stride-5 banks, conflict-free
    int chunk = blockIdx.x;           // 0..11 (64-channel chunk)
    int b     = blockIdx.y;           // 0..255
    int c0 = chunk * 64;
    const float* xb = x + ((size_t)b * CHAN + c0) * HW;
    for (int t = threadIdx.x; t < 64 * HW; t += 256) {
        int j = t / HW, p = t - j * HW;
        lds[j * 197 + p] = xb[t];     // coalesced read of 64 full channels
    }
    if (chunk == 0) {                 // per-batch: init pred rows to b3, write deltaxy
        float b30 = b3[0], b31 = b3[1];
        for (int i = threadIdx.x; i < SPS * 2; i += 256) {
            int idx = b * SPS * 2 + i;
            out[idx] = (i & 1) ? b31 : b30;                          // pred init (atomics add on top)
            out[MROWS * 2 + idx] = (float)(pxs[idx] - pys[idx]) + 13.0f;  // (H-1)=13
        }
    }
    __syncthreads();
    int w = threadIdx.x >> 6, lane = threadIdx.x & 63;
    for (int s = w; s < SPS; s += 4) {
        int base = (b * SPS + s) * 2;
        int ix = pxs[base] * 14 + pxs[base + 1];
        int iy = pys[base] * 14 + pys[base + 1];
        size_t ro = (size_t)(b * SPS + s) * K1;
        feats[ro + c0 + lane]        = f2bf(lds[lane * 197 + ix]);  // 128B coalesced store
        feats[ro + CHAN + c0 + lane] = f2bf(lds[lane * 197 + iy]);
    }
}

// ---------- 128xFULL-N bf16 MFMA GEMM, issue-early double buffer, T2 swizzle, T5 ----------
// C = relu(A @ Bt^T + bias); A[M][K], Bt[N=512][K] row-major bf16.
// Grid = M/128 (no N tiling): each A panel staged ONCE; B (<=1.5MB) is L2-hot.
// LDS half: slot(row, c16) holds global chunk c16 ^ (row&7)  [T2 both-sides swizzle]
// predMode: accumulate pred = relu(C)@W3 into out via atomics (bias=b2) instead of storing C.
__global__ __launch_bounds__(512, 2) void gemm_fullN(const unsigned short* __restrict__ A,
                                                     const unsigned short* __restrict__ Bt,
                                                     const float* __restrict__ bias,
                                                     unsigned short* __restrict__ C,
                                                     const float* __restrict__ W3,
                                                     float* __restrict__ out,
                                                     int Kd, int predMode) {
    extern __shared__ char smem[];    // 2 * (A[128][64] + B[512][64]) bf16 = 163840 B
    int t = threadIdx.x;
    int wid = t >> 6, lane = t & 63;
    int wr = wid >> 2, wcn = wid & 3;            // 2M x 4N waves; wave owns 64 rows x 128 cols
    int lr = lane & 15, lk = lane >> 4;
    int mBase = blockIdx.x * 128;
    f32x4 acc[4][8] = {};
    int nK = Kd >> 6;

    // stage K-tile tt into buf[tt&1]: A 2 loads + B 8 loads per thread; inverse-swizzled src
    auto stage = [&](int tt) {
        char* Ab = smem + (tt & 1) * BUFB;
        char* Bb = Ab + ABUF;
        int k0 = tt << 6;
        #pragma unroll
        for (int i = 0; i < 2; ++i) {
            int lin = i * 512 + t;
            int row = lin >> 3;
            int cs  = (lin & 7) ^ (row & 7);
            gload_lds16((const char*)(A + ((size_t)(mBase + row) * Kd + k0 + cs * 8)),
                        Ab + lin * 16);
        }
        #pragma unroll
        for (int i = 0; i < 8; ++i) {
            int lin = i * 512 + t;
            int row = lin >> 3;
            int cs  = (lin & 7) ^ (row & 7);
            gload_lds16((const char*)(Bt + ((size_t)row * Kd + k0 + cs * 8)),
                        Bb + lin * 16);
        }
    };
    // compute K-tile tt from buf[tt&1]; swizzled ds_read addresses
    auto compute = [&](int tt) {
        const unsigned short* Ab = (const unsigned short*)(smem + (tt & 1) * BUFB);
        const unsigned short* Bb = Ab + ABUF / 2;
        #pragma unroll
        for (int kk = 0; kk < 2; ++kk) {
            short8 af[4], bfr[8];
            #pragma unroll
            for (int m = 0; m < 4; ++m) {
                int row = wr * 64 + m * 16 + lr;
                af[m] = *(const short8*)(&Ab[row * 64 + (((kk * 4 + lk) ^ (row & 7)) * 8)]);
            }
            #pragma unroll
            for (int n = 0; n < 8; ++n) {
                int row = wcn * 128 + n * 16 + lr;
                bfr[n] = *(const short8*)(&Bb[row * 64 + (((kk * 4 + lk) ^ (row & 7)) * 8)]);
            }
            __builtin_amdgcn_s_setprio(1);
            #pragma unroll
            for (int m = 0; m < 4; ++m)
                #pragma unroll
                for (int n = 0; n < 8; ++n)
                    acc[m][n] = __builtin_amdgcn_mfma_f32_16x16x32_bf16(af[m], bfr[n], acc[m][n], 0, 0, 0);
            __builtin_amdgcn_s_setprio(0);
        }
    };

    stage(0);
    asm volatile("s_waitcnt vmcnt(0)" ::: "memory");
    __builtin_amdgcn_s_barrier();
    for (int tt = 0; tt < nK; ++tt) {
        if (tt + 1 < nK) stage(tt + 1);          // issue-early: flies under compute(tt)
        compute(tt);
        asm volatile("s_waitcnt vmcnt(0)" ::: "memory");   // next tile resident
        __builtin_amdgcn_s_barrier();
    }

    if (!predMode) {
        // epilogue: bias + relu + bf16 store.  C row=(lane>>4)*4+j, col=lane&15 (m89-verified)
        #pragma unroll
        for (int n = 0; n < 8; ++n) {
            int c = wcn * 128 + n * 16 + lr;
            float bv = bias[c];
            #pragma unroll
            for (int m = 0; m < 4; ++m) {
                int r0 = mBase + wr * 64 + m * 16 + lk * 4;
                #pragma unroll
                for (int j = 0; j < 4; ++j)
                    C[(size_t)(r0 + j) * HID + c] = f2bf(fmaxf(acc[m][n][j] + bv, 0.f));
            }
        }
    } else {
        // fused final layer: pred[r][o] += sum_c relu(acc+b2)[r][c] * W3[c][o]
        float w3v[8][2], bv[8];
        #pragma unroll
        for (int n = 0; n < 8; ++n) {
            int c = wcn * 128 + n * 16 + lr;
            w3v[n][0] = W3[c * 2 + 0];
            w3v[n][1] = W3[c * 2 + 1];
            bv[n] = bias[c];
        }
        #pragma unroll
        for (int m = 0; m < 4; ++m) {
            #pragma unroll
            for (int j = 0; j < 4; ++j) {
                float p0 = 0.f, p1 = 0.f;
                #pragma unroll
                for (int n = 0; n < 8; ++n) {
                    float v = fmaxf(acc[m][n][j] + bv[n], 0.f);
                    p0 += v * w3v[n][0];
                    p1 += v * w3v[n][1];
                }
                #pragma unroll
                for (int msk = 1; msk < 16; msk <<= 1) {   // reduce over the 16 lr-lanes (same row)
                    p0 += __shfl_xor(p0, msk);
                    p1 += __shfl_xor(p1, msk);
                }
                if (lr == 0) {
                    int r = mBase + wr * 64 + m * 16 + lk * 4 + j;
                    atomicAdd(&out[r * 2 + 0], p0);   // 4 wcn-wave partials per row
                    atomicAdd(&out[r * 2 + 1], p1);
                }
            }
        }
    }
}

// ---------- launch ----------
extern "C" void kernel_launch(void* const* d_in, const int* in_sizes, int n_in,
                              void* d_out, int out_size, void* d_ws, size_t ws_size,
                              hipStream_t stream) {
    const float* x  = (const float*)d_in[0];
    const float* W1 = (const float*)d_in[1];
    const float* b1 = (const float*)d_in[2];
    const float* W2 = (const float*)d_in[3];
    const float* b2 = (const float*)d_in[4];
    const float* W3 = (const float*)d_in[5];
    const float* b3 = (const float*)d_in[6];
    const int*  pxs = (const int*)d_in[7];
    const int*  pys = (const int*)d_in[8];
    float* out = (float*)d_out;
    char* ws = (char*)d_ws;

    // ws layout (bytes)
    unsigned short* W1t   = (unsigned short*)(ws + 0);          // 512x1536 bf16 = 1,572,864
    unsigned short* W2t   = (unsigned short*)(ws + 1572864);    // 512x512  bf16 =   524,288
    unsigned short* h1    = (unsigned short*)(ws + 2099200);    // 50176x512 bf16 = 51,380,224
    unsigned short* feats = (unsigned short*)(ws + 53479424);   // 50176x1536 bf16 = 154,140,672

    // allow 160KB dynamic LDS (attribute set is not a stream op; safe under capture)
    hipFuncSetAttribute((const void*)gemm_fullN,
                        hipFuncAttributeMaxDynamicSharedMemorySize, 2 * BUFB);

    transpose_cast<<<(K1 * HID + 255) / 256, 256, 0, stream>>>(W1, W1t, K1, HID);
    transpose_cast<<<(HID * HID + 255) / 256, 256, 0, stream>>>(W2, W2t, HID, HID);
    // gather also initializes out: pred rows = b3 (GEMM2 atomics accumulate), deltaxy written
    gather_feats<<<dim3(12, BATCH), 256, 0, stream>>>(x, pxs, pys, b3, feats, out);
    // GEMM1: h1 = relu(feats @ W1t^T + b1)   grid = 392 (M-tiles only; A staged once)
    gemm_fullN<<<MROWS / 128, 512, 2 * BUFB, stream>>>(
        feats, W1t, b1, h1, nullptr, nullptr, K1, 0);
    // GEMM2 (+fused GEMM3): out[0:2M) += relu(h1 @ W2t^T + b2) @ W3
    gemm_fullN<<<MROWS / 128, 512, 2 * BUFB, stream>>>(
        h1, W2t, b2, nullptr, W3, out, HID, 1);
}